// Round 1
// baseline (550.269 us; speedup 1.0000x reference)
//
#include <hip/hip_runtime.h>
#include <hip/hip_bf16.h>

// Equivariant decoder: r=|v| -> MLP(fp32) -> r_dec -> t=einsum('bi,ijp')(bf16 MFMA)
//                      -> out_vec=einsum('bjp,bjm')/C (fp32) -> [P x 1o | Q zeros]
// N=1024, C=256, P=512, F=768, out stride 6656.
// Workspace layout (needs ~93 MB):
//   [0, 67108864)              Wtp bf16 in 32x32x16-MFMA A-fragment order
//   [67108864, 67633152)       r_dec bf16 row-major [1024][256]
//   [67633152, 92798976)       j-split partial outputs fp32 [4][1024][512*3]

#define N_G   1024
#define C_DIM 256
#define P_DIM 512
#define F_DIM 768
#define OUT_STRIDE 6656
#define VEC_LEN 1536

typedef short  short8  __attribute__((ext_vector_type(8)));
typedef float  f32x16  __attribute__((ext_vector_type(16)));

static __device__ __forceinline__ unsigned short f32_bf16(float f){
  unsigned u = __builtin_bit_cast(unsigned, f);
  u = (u + 0x7fffu + ((u >> 16) & 1u)) >> 16;   // RNE
  return (unsigned short)u;
}

static __device__ __forceinline__ float gelu_tanh(float x){
  float u = 0.7978845608028654f * (x + 0.044715f * x * x * x);
  return 0.5f * x * (1.0f + tanhf(u));
}

// ---------------- prepack: Wtp fp32 [i=256][j=256][p=512] -> bf16 A-fragment order
// unit = (j*16 + pt)*16 + ik ; lane holds p = pt*32+(lane&31), k-slice i = ik*16+(lane>>5)*8+e
// A/B use the SAME lane->k formula, so any within-K mapping error cancels in the MFMA dot.
__global__ __launch_bounds__(256) void k_prepack(const float* __restrict__ wtp,
                                                 unsigned short* __restrict__ frag){
  int tid  = blockIdx.x * 256 + threadIdx.x;   // 4,194,304 threads
  int unit = tid >> 6, lane = tid & 63;
  int j  = unit >> 8;
  int pt = (unit >> 4) & 15;
  int ik = unit & 15;
  int p  = pt * 32 + (lane & 31);
  int i0 = ik * 16 + (lane >> 5) * 8;
  const float* src = wtp + (size_t)i0 * (C_DIM * P_DIM) + j * P_DIM + p;
  short8 v;
  #pragma unroll
  for (int e = 0; e < 8; ++e)
    v[e] = (short)f32_bf16(src[(size_t)e * (C_DIM * P_DIM)]);
  *reinterpret_cast<short8*>(frag + (size_t)unit * 512 + lane * 8) = v;
}

// ---------------- fused MLP (fp32): 4 rows per 256-thread block
__global__ __launch_bounds__(256) void k_mlp(const float* __restrict__ enc,
    const float* __restrict__ W0,  const float* __restrict__ b0,
    const float* __restrict__ g0,  const float* __restrict__ be0,
    const float* __restrict__ W1,  const float* __restrict__ b1,
    const float* __restrict__ g1,  const float* __restrict__ be1,
    const float* __restrict__ Wout,const float* __restrict__ bout,
    unsigned short* __restrict__ rdec){
  __shared__ float r_s[4][C_DIM];
  __shared__ float hA[4][F_DIM];
  __shared__ float hB[4][F_DIM];
  __shared__ float stat[4][2];
  int t = threadIdx.x;
  int brow = blockIdx.x * 4;

  // r = per-channel vector norms
  #pragma unroll
  for (int rr = 0; rr < 4; ++rr){
    const float* e = enc + (size_t)(brow + rr) * F_DIM + t * 3;
    float x = e[0], y = e[1], z = e[2];
    r_s[rr][t] = sqrtf(x*x + y*y + z*z);
  }
  __syncthreads();

  // ---- layer 0: X = r@W0 + b0 ; LN(g0,be0) ; gelu -> hA
  float xa[4][3];
  #pragma unroll
  for (int rr = 0; rr < 4; ++rr){ xa[rr][0]=0.f; xa[rr][1]=0.f; xa[rr][2]=0.f; }
  for (int k = 0; k < C_DIM; ++k){
    float w0 = W0[k*F_DIM + t], w1 = W0[k*F_DIM + t + 256], w2 = W0[k*F_DIM + t + 512];
    #pragma unroll
    for (int rr = 0; rr < 4; ++rr){
      float rv = r_s[rr][k];
      xa[rr][0] += rv*w0; xa[rr][1] += rv*w1; xa[rr][2] += rv*w2;
    }
  }
  {
    float c0 = b0[t], c1 = b0[t+256], c2 = b0[t+512];
    #pragma unroll
    for (int rr = 0; rr < 4; ++rr){ xa[rr][0]+=c0; xa[rr][1]+=c1; xa[rr][2]+=c2; }
  }
  #pragma unroll
  for (int rr = 0; rr < 4; ++rr){ hA[rr][t]=xa[rr][0]; hA[rr][t+256]=xa[rr][1]; hA[rr][t+512]=xa[rr][2]; }
  __syncthreads();
  {
    int w = t >> 6, lane = t & 63;
    float s = 0.f, s2 = 0.f;
    for (int q = lane; q < F_DIM; q += 64){ float x = hA[w][q]; s += x; s2 += x*x; }
    #pragma unroll
    for (int off = 32; off; off >>= 1){ s += __shfl_down(s, off); s2 += __shfl_down(s2, off); }
    if (lane == 0){ float mu = s/F_DIM; float var = s2/F_DIM - mu*mu;
                    stat[w][0] = mu; stat[w][1] = rsqrtf(var + 1e-5f); }
  }
  __syncthreads();
  {
    float G0 = g0[t], G1 = g0[t+256], G2 = g0[t+512];
    float E0 = be0[t], E1 = be0[t+256], E2 = be0[t+512];
    #pragma unroll
    for (int rr = 0; rr < 4; ++rr){
      float mu = stat[rr][0], rs = stat[rr][1];
      hA[rr][t]     = gelu_tanh((xa[rr][0]-mu)*rs*G0 + E0);
      hA[rr][t+256] = gelu_tanh((xa[rr][1]-mu)*rs*G1 + E1);
      hA[rr][t+512] = gelu_tanh((xa[rr][2]-mu)*rs*G2 + E2);
    }
  }
  __syncthreads();

  // ---- layer 1: X = hA@W1 + b1 ; LN(g1,be1) ; gelu -> hB
  float xb[4][3];
  #pragma unroll
  for (int rr = 0; rr < 4; ++rr){ xb[rr][0]=0.f; xb[rr][1]=0.f; xb[rr][2]=0.f; }
  for (int k = 0; k < F_DIM; ++k){
    float w0 = W1[k*F_DIM + t], w1 = W1[k*F_DIM + t + 256], w2 = W1[k*F_DIM + t + 512];
    #pragma unroll
    for (int rr = 0; rr < 4; ++rr){
      float hv = hA[rr][k];
      xb[rr][0] += hv*w0; xb[rr][1] += hv*w1; xb[rr][2] += hv*w2;
    }
  }
  {
    float c0 = b1[t], c1 = b1[t+256], c2 = b1[t+512];
    #pragma unroll
    for (int rr = 0; rr < 4; ++rr){ xb[rr][0]+=c0; xb[rr][1]+=c1; xb[rr][2]+=c2; }
  }
  #pragma unroll
  for (int rr = 0; rr < 4; ++rr){ hB[rr][t]=xb[rr][0]; hB[rr][t+256]=xb[rr][1]; hB[rr][t+512]=xb[rr][2]; }
  __syncthreads();
  {
    int w = t >> 6, lane = t & 63;
    float s = 0.f, s2 = 0.f;
    for (int q = lane; q < F_DIM; q += 64){ float x = hB[w][q]; s += x; s2 += x*x; }
    #pragma unroll
    for (int off = 32; off; off >>= 1){ s += __shfl_down(s, off); s2 += __shfl_down(s2, off); }
    if (lane == 0){ float mu = s/F_DIM; float var = s2/F_DIM - mu*mu;
                    stat[w][0] = mu; stat[w][1] = rsqrtf(var + 1e-5f); }
  }
  __syncthreads();
  {
    float G0 = g1[t], G1 = g1[t+256], G2 = g1[t+512];
    float E0 = be1[t], E1 = be1[t+256], E2 = be1[t+512];
    #pragma unroll
    for (int rr = 0; rr < 4; ++rr){
      float mu = stat[rr][0], rs = stat[rr][1];
      hB[rr][t]     = gelu_tanh((xb[rr][0]-mu)*rs*G0 + E0);
      hB[rr][t+256] = gelu_tanh((xb[rr][1]-mu)*rs*G1 + E1);
      hB[rr][t+512] = gelu_tanh((xb[rr][2]-mu)*rs*G2 + E2);
    }
  }
  __syncthreads();

  // ---- out layer: r_dec = hB@Wout + bout -> bf16
  float oa[4] = {0.f, 0.f, 0.f, 0.f};
  for (int k = 0; k < F_DIM; ++k){
    float wv = Wout[k*C_DIM + t];
    #pragma unroll
    for (int rr = 0; rr < 4; ++rr) oa[rr] += hB[rr][k] * wv;
  }
  float bo = bout[t];
  #pragma unroll
  for (int rr = 0; rr < 4; ++rr)
    rdec[(size_t)(brow + rr) * C_DIM + t] = f32_bf16(oa[rr] + bo);
}

// ---------------- main fused TP: t[p,b] = sum_i Wtp[i,j,p]*rdec[b,i] (MFMA 32x32x16 bf16),
// then out[b,p,m] += t[p,b]*v[b,j,m] on VALU. D[p,b]: lane owns ONE b-column (col=lane&31).
// grid 256 = pt(16) x bblk(4) x js(4); block 512 thr = 8 waves x (32p x 32b); 64 j per block.
__global__ __launch_bounds__(512, 2) void k_tp(const unsigned short* __restrict__ frag,
    const unsigned short* __restrict__ rdec, const float* __restrict__ enc,
    float* __restrict__ part){
  int bx   = blockIdx.x;
  int pt   = bx & 15;
  int bblk = (bx >> 4) & 3;
  int js   = bx >> 6;
  int w    = threadIdx.x >> 6;
  int lane = threadIdx.x & 63;
  int b    = bblk * 256 + w * 32 + (lane & 31);
  int g    = lane >> 5;

  // resident B-fragments: rdec[b, i] for all 16 K-chunks (64 VGPR)
  short8 bf[16];
  #pragma unroll
  for (int ik = 0; ik < 16; ++ik)
    bf[ik] = *reinterpret_cast<const short8*>(rdec + (size_t)b * C_DIM + ik * 16 + g * 8);

  float oacc[48];
  #pragma unroll
  for (int q = 0; q < 48; ++q) oacc[q] = 0.f;

  int j0 = js * 64;
  for (int j = j0; j < j0 + 64; ++j){
    const unsigned short* fb = frag + ((size_t)(j * 16 + pt) * 16) * 512 + lane * 8;
    f32x16 acc = {};
    #pragma unroll
    for (int ik = 0; ik < 16; ++ik){
      short8 a = *reinterpret_cast<const short8*>(fb + (size_t)ik * 512);
      acc = __builtin_amdgcn_mfma_f32_32x32x16_bf16(a, bf[ik], acc, 0, 0, 0);
    }
    const float* vp = enc + (size_t)b * F_DIM + j * 3;
    float v0 = vp[0], v1 = vp[1], v2 = vp[2];
    #pragma unroll
    for (int r = 0; r < 16; ++r){
      oacc[r*3+0] += acc[r] * v0;
      oacc[r*3+1] += acc[r] * v1;
      oacc[r*3+2] += acc[r] * v2;
    }
  }

  float* pb = part + (size_t)(js * N_G + b) * VEC_LEN;
  #pragma unroll
  for (int r = 0; r < 16; ++r){
    int p = pt * 32 + (r & 3) + 8 * (r >> 2) + 4 * g;   // verified C/D row map (m74/m101)
    pb[p*3+0] = oacc[r*3+0];
    pb[p*3+1] = oacc[r*3+1];
    pb[p*3+2] = oacc[r*3+2];
  }
}

// ---------------- reduce 4 j-partials * (1/C), write structural zeros
__global__ __launch_bounds__(256) void k_reduce(const float* __restrict__ part,
                                                float* __restrict__ out){
  int idx = blockIdx.x * 256 + threadIdx.x;
  if (idx >= N_G * OUT_STRIDE) return;
  int b = idx / OUT_STRIDE;
  int q = idx - b * OUT_STRIDE;
  float val = 0.f;
  if (q < VEC_LEN){
    size_t base = (size_t)b * VEC_LEN + q;
    const size_t st = (size_t)N_G * VEC_LEN;
    val = (part[base] + part[base + st] + part[base + 2*st] + part[base + 3*st]) * (1.0f / C_DIM);
  }
  out[idx] = val;
}

extern "C" void kernel_launch(void* const* d_in, const int* in_sizes, int n_in,
                              void* d_out, int out_size, void* d_ws, size_t ws_size,
                              hipStream_t stream){
  const float* enc  = (const float*)d_in[0];
  const float* W0   = (const float*)d_in[1];
  const float* b0   = (const float*)d_in[2];
  const float* g0   = (const float*)d_in[3];
  const float* be0  = (const float*)d_in[4];
  const float* W1   = (const float*)d_in[5];
  const float* b1   = (const float*)d_in[6];
  const float* g1   = (const float*)d_in[7];
  const float* be1  = (const float*)d_in[8];
  const float* Wout = (const float*)d_in[9];
  const float* bout = (const float*)d_in[10];
  const float* Wtp  = (const float*)d_in[11];
  float* out = (float*)d_out;

  char* ws = (char*)d_ws;
  unsigned short* frag = (unsigned short*)(ws);                       // 67,108,864 B
  unsigned short* rdec = (unsigned short*)(ws + 67108864);            //    524,288 B
  float*          part = (float*)(ws + 67108864 + 524288);            // 25,165,824 B

  hipLaunchKernelGGL(k_prepack, dim3(16384), dim3(256), 0, stream, Wtp, frag);
  hipLaunchKernelGGL(k_mlp,     dim3(256),   dim3(256), 0, stream, enc,
                     W0, b0, g0, be0, W1, b1, g1, be1, Wout, bout, rdec);
  hipLaunchKernelGGL(k_tp,      dim3(256),   dim3(512), 0, stream, frag, rdec, enc, part);
  hipLaunchKernelGGL(k_reduce,  dim3((N_G * OUT_STRIDE + 255) / 256), dim3(256), 0, stream,
                     part, out);
}

// Round 3
// 432.986 us; speedup vs baseline: 1.2709x; 1.2709x over previous
//
#include <hip/hip_runtime.h>
#include <hip/hip_bf16.h>

// Equivariant decoder: r=|v| -> MLP(fp32, tiled GEMM kernels) -> r_dec bf16
//   -> t=einsum('bi,ijp') via bf16 MFMA (LDS-staged A, double-buffered)
//   -> out_vec=einsum('bjp,bjm')/C fused in-register -> [P x 1o | Q zeros]
// N=1024, C=256, P=512, F=768, out stride 6656.
// Workspace:
//   [0, 67108864)        Wtp bf16 in 32x32x16-MFMA A-fragment order
//   [67108864, 67633152) r_dec bf16 [1024][256]
//   [67633152, 92798976) part fp32 [4][1024][1536]  (also reused EARLIER in the
//                        stream for MLP temps: r 1MB, bufA 3MB, bufB 3MB)

#define N_G   1024
#define C_DIM 256
#define P_DIM 512
#define F_DIM 768
#define OUT_STRIDE 6656
#define VEC_LEN 1536

typedef short  short8  __attribute__((ext_vector_type(8)));
typedef float  f32x16  __attribute__((ext_vector_type(16)));

#define GLOAD_LDS16(GP, LP)                                                    \
  __builtin_amdgcn_global_load_lds(                                            \
      (const __attribute__((address_space(1))) void*)(GP),                     \
      (__attribute__((address_space(3))) void*)(LP), 16, 0, 0)

static __device__ __forceinline__ unsigned short f32_bf16(float f){
  unsigned u = __builtin_bit_cast(unsigned, f);
  u = (u + 0x7fffu + ((u >> 16) & 1u)) >> 16;   // RNE
  return (unsigned short)u;
}

static __device__ __forceinline__ float gelu_tanh(float x){
  float u = 0.7978845608028654f * (x + 0.044715f * x * x * x);
  return 0.5f * x * (1.0f + tanhf(u));
}

// ---------------- prepack: Wtp fp32 [i=256][j=256][p=512] -> bf16 A-fragment order
// unit = (j*16 + pt)*16 + ik ; lane p = pt*32+(lane&31), k = ik*16+(lane>>5)*8+e
__global__ __launch_bounds__(256) void k_prepack(const float* __restrict__ wtp,
                                                 unsigned short* __restrict__ frag){
  int tid  = blockIdx.x * 256 + threadIdx.x;
  int unit = tid >> 6, lane = tid & 63;
  int j  = unit >> 8;
  int pt = (unit >> 4) & 15;
  int ik = unit & 15;
  int p  = pt * 32 + (lane & 31);
  int i0 = ik * 16 + (lane >> 5) * 8;
  const float* src = wtp + (size_t)i0 * (C_DIM * P_DIM) + j * P_DIM + p;
  short8 v;
  #pragma unroll
  for (int e = 0; e < 8; ++e)
    v[e] = (short)f32_bf16(src[(size_t)e * (C_DIM * P_DIM)]);
  *reinterpret_cast<short8*>(frag + (size_t)unit * 512 + lane * 8) = v;
}

// ---------------- r = per-channel vector norms: [1024][256]
__global__ __launch_bounds__(256) void k_norm(const float* __restrict__ enc,
                                              float* __restrict__ r){
  int b = blockIdx.x, t = threadIdx.x;
  const float* e = enc + (size_t)b * F_DIM + t * 3;
  r[(size_t)b * C_DIM + t] = sqrtf(e[0]*e[0] + e[1]*e[1] + e[2]*e[2]);
}

// ---------------- tiled fp32 GEMM: C[M,N] = A[M,K]@B[K,N] + bias
// BM=16, BN=64, BK=64; 64 threads (1 wave); thread tile 4x4 (rg=tid/16, cg=tid%16)
template<bool OBF>
__global__ __launch_bounds__(64) void k_gemm(const float* __restrict__ A,
    const float* __restrict__ B, const float* __restrict__ bias,
    float* __restrict__ C, unsigned short* __restrict__ Cb,
    int M, int N, int K){
  __shared__ __align__(16) float Ast[64][20];   // [kk][r], padded (stride 80B, 16B-mult)
  __shared__ __align__(16) float Bs[64][64];    // [kk][c]
  int nbc = N >> 6;
  int mb = blockIdx.x / nbc, nb = blockIdx.x % nbc;
  int m0 = mb * 16, n0 = nb * 64;
  int t  = threadIdx.x;
  int cg = t & 15, rg = t >> 4;

  float acc[4][4];
  #pragma unroll
  for (int i = 0; i < 4; ++i)
    #pragma unroll
    for (int jj = 0; jj < 4; ++jj) acc[i][jj] = 0.f;

  int nch = K >> 6;
  for (int ch = 0; ch < nch; ++ch){
    int k0 = ch << 6;
    // stage A[16][64] transposed -> Ast[kk][r]
    #pragma unroll
    for (int it = 0; it < 16; ++it)
      Ast[t][it] = A[(size_t)(m0 + it) * K + k0 + t];
    // stage B[64][64] -> Bs[kk][c]
    #pragma unroll
    for (int it = 0; it < 64; ++it)
      Bs[it][t] = B[(size_t)(k0 + it) * N + n0 + t];
    __syncthreads();
    #pragma unroll 8
    for (int kk = 0; kk < 64; ++kk){
      float4 av = *reinterpret_cast<const float4*>(&Ast[kk][rg * 4]);
      float4 bv = *reinterpret_cast<const float4*>(&Bs[kk][cg * 4]);
      acc[0][0] += av.x*bv.x; acc[0][1] += av.x*bv.y; acc[0][2] += av.x*bv.z; acc[0][3] += av.x*bv.w;
      acc[1][0] += av.y*bv.x; acc[1][1] += av.y*bv.y; acc[1][2] += av.y*bv.z; acc[1][3] += av.y*bv.w;
      acc[2][0] += av.z*bv.x; acc[2][1] += av.z*bv.y; acc[2][2] += av.z*bv.z; acc[2][3] += av.z*bv.w;
      acc[3][0] += av.w*bv.x; acc[3][1] += av.w*bv.y; acc[3][2] += av.w*bv.z; acc[3][3] += av.w*bv.w;
    }
    __syncthreads();
  }

  #pragma unroll
  for (int i = 0; i < 4; ++i){
    int row = m0 + rg * 4 + i;
    #pragma unroll
    for (int jj = 0; jj < 4; ++jj){
      int col = n0 + cg * 4 + jj;
      float val = acc[i][jj] + bias[col];
      if (OBF) Cb[(size_t)row * N + col] = f32_bf16(val);
      else     C [(size_t)row * N + col] = val;
    }
  }
}

// ---------------- LayerNorm + GELU over rows of 768: wave per row, 4 rows/block
__global__ __launch_bounds__(256) void k_ln(const float* __restrict__ X,
    const float* __restrict__ g, const float* __restrict__ be,
    float* __restrict__ Y){
  int w = threadIdx.x >> 6, lane = threadIdx.x & 63;
  int row = blockIdx.x * 4 + w;
  const float* x = X + (size_t)row * F_DIM;
  float v[12];
  float s = 0.f, s2 = 0.f;
  #pragma unroll
  for (int i = 0; i < 12; ++i){
    v[i] = x[lane + i * 64];
    s += v[i]; s2 += v[i] * v[i];
  }
  #pragma unroll
  for (int off = 32; off; off >>= 1){ s += __shfl_down(s, off); s2 += __shfl_down(s2, off); }
  s = __shfl(s, 0); s2 = __shfl(s2, 0);
  float mu = s * (1.0f / F_DIM);
  float rs = rsqrtf(s2 * (1.0f / F_DIM) - mu * mu + 1e-5f);
  float* y = Y + (size_t)row * F_DIM;
  #pragma unroll
  for (int i = 0; i < 12; ++i){
    int c = lane + i * 64;
    y[c] = gelu_tanh((v[i] - mu) * rs * g[c] + be[c]);
  }
}

// ---------------- main fused TP: LDS-staged A (dbuf), B (rdec) register-resident.
// grid 256 = pt(16) x bblk(4) x js(4); block 512 = 8 waves x (32p x 32b); 64 j/block.
__global__ __launch_bounds__(512, 2) void k_tp(const unsigned short* __restrict__ frag,
    const unsigned short* __restrict__ rdec, const float* __restrict__ enc,
    float* __restrict__ part){
  __shared__ unsigned short As[2][8192];     // 2 x 16KB j-tiles
  int bx   = blockIdx.x;
  int pt   = bx & 15;
  int bblk = (bx >> 4) & 3;
  int js   = bx >> 6;
  int w    = threadIdx.x >> 6;
  int lane = threadIdx.x & 63;
  int b    = bblk * 256 + w * 32 + (lane & 31);
  int g    = lane >> 5;

  short8 bf[16];
  #pragma unroll
  for (int ik = 0; ik < 16; ++ik)
    bf[ik] = *reinterpret_cast<const short8*>(rdec + (size_t)b * C_DIM + ik * 16 + g * 8);

  float oacc[48];
  #pragma unroll
  for (int q = 0; q < 48; ++q) oacc[q] = 0.f;

  int j0 = js * 64;
  // stage j-tile (16 units x 1KB) into As[buf]; 2 units per wave; dest = base + lane*16
  #define STAGE(BUF, J) do {                                                        \
    _Pragma("unroll")                                                               \
    for (int uu = 0; uu < 2; ++uu){                                                 \
      int u = w * 2 + uu;                                                           \
      const unsigned short* gp = frag + ((size_t)(((J) * 16 + pt) * 16 + u)) * 512  \
                                 + lane * 8;                                        \
      GLOAD_LDS16(gp, &As[BUF][u * 512]);                                           \
    } } while (0)

  STAGE(0, j0);
  __syncthreads();          // drains vmcnt before barrier -> tile 0 ready
  int cur = 0;
  for (int j = j0; j < j0 + 64; ++j){
    if (j < j0 + 63) STAGE(cur ^ 1, j + 1);
    f32x16 acc = {};
    #pragma unroll
    for (int ik = 0; ik < 16; ++ik){
      short8 a = *reinterpret_cast<const short8*>(&As[cur][ik * 512 + lane * 8]);
      acc = __builtin_amdgcn_mfma_f32_32x32x16_bf16(a, bf[ik], acc, 0, 0, 0);
    }
    const float* vp = enc + (size_t)b * F_DIM + j * 3;
    float v0 = vp[0], v1 = vp[1], v2 = vp[2];
    #pragma unroll
    for (int r = 0; r < 16; ++r){
      oacc[r*3+0] += acc[r] * v0;
      oacc[r*3+1] += acc[r] * v1;
      oacc[r*3+2] += acc[r] * v2;
    }
    __syncthreads();        // next tile landed (vmcnt) + everyone done reading cur
    cur ^= 1;
  }

  float* pb = part + (size_t)(js * N_G + b) * VEC_LEN;
  #pragma unroll
  for (int r = 0; r < 16; ++r){
    int p = pt * 32 + (r & 3) + 8 * (r >> 2) + 4 * g;   // verified C/D row map (m74/m101)
    pb[p*3+0] = oacc[r*3+0];
    pb[p*3+1] = oacc[r*3+1];
    pb[p*3+2] = oacc[r*3+2];
  }
}

// ---------------- reduce 4 j-partials * (1/C), write structural zeros
__global__ __launch_bounds__(256) void k_reduce(const float* __restrict__ part,
                                                float* __restrict__ out){
  int idx = blockIdx.x * 256 + threadIdx.x;
  if (idx >= N_G * OUT_STRIDE) return;
  int b = idx / OUT_STRIDE;
  int q = idx - b * OUT_STRIDE;
  float val = 0.f;
  if (q < VEC_LEN){
    size_t base = (size_t)b * VEC_LEN + q;
    const size_t st = (size_t)N_G * VEC_LEN;
    val = (part[base] + part[base + st] + part[base + 2*st] + part[base + 3*st]) * (1.0f / C_DIM);
  }
  out[idx] = val;
}

extern "C" void kernel_launch(void* const* d_in, const int* in_sizes, int n_in,
                              void* d_out, int out_size, void* d_ws, size_t ws_size,
                              hipStream_t stream){
  const float* enc  = (const float*)d_in[0];
  const float* W0   = (const float*)d_in[1];
  const float* b0   = (const float*)d_in[2];
  const float* g0   = (const float*)d_in[3];
  const float* be0  = (const float*)d_in[4];
  const float* W1   = (const float*)d_in[5];
  const float* b1   = (const float*)d_in[6];
  const float* g1   = (const float*)d_in[7];
  const float* be1  = (const float*)d_in[8];
  const float* Wout = (const float*)d_in[9];
  const float* bout = (const float*)d_in[10];
  const float* Wtp  = (const float*)d_in[11];
  float* out = (float*)d_out;

  char* ws = (char*)d_ws;
  unsigned short* frag = (unsigned short*)(ws);                 // 67,108,864 B
  unsigned short* rdec = (unsigned short*)(ws + 67108864);      //    524,288 B
  float*          part = (float*)(ws + 67633152);               // 25,165,824 B
  // MLP temps live inside the (not-yet-written) part region:
  float* rbuf = (float*)(ws + 67633152);                        // 1 MB
  float* bufA = (float*)(ws + 67633152 + 1048576);              // 3 MB
  float* bufB = (float*)(ws + 67633152 + 1048576 + 3145728);    // 3 MB

  hipLaunchKernelGGL(k_prepack, dim3(16384), dim3(256), 0, stream, Wtp, frag);
  hipLaunchKernelGGL(k_norm,    dim3(N_G),   dim3(256), 0, stream, enc, rbuf);
  hipLaunchKernelGGL((k_gemm<false>), dim3(64 * 12), dim3(64), 0, stream,
                     rbuf, W0, b0, bufA, rdec, N_G, F_DIM, C_DIM);
  hipLaunchKernelGGL(k_ln,      dim3(256),   dim3(256), 0, stream, bufA, g0, be0, bufB);
  hipLaunchKernelGGL((k_gemm<false>), dim3(64 * 12), dim3(64), 0, stream,
                     bufB, W1, b1, bufA, rdec, N_G, F_DIM, F_DIM);
  hipLaunchKernelGGL(k_ln,      dim3(256),   dim3(256), 0, stream, bufA, g1, be1, bufB);
  hipLaunchKernelGGL((k_gemm<true>),  dim3(64 * 4),  dim3(64), 0, stream,
                     bufB, Wout, bout, bufA, rdec, N_G, C_DIM, F_DIM);
  hipLaunchKernelGGL(k_tp,      dim3(256),   dim3(512), 0, stream, frag, rdec, enc, part);
  hipLaunchKernelGGL(k_reduce,  dim3((N_G * OUT_STRIDE + 255) / 256), dim3(256), 0, stream,
                     part, out);
}